// Round 1
// baseline (12714.739 us; speedup 1.0000x reference)
//
#include <hip/hip_runtime.h>
#include <hip/hip_bf16.h>
#include <stdint.h>

typedef unsigned long long u64;

#define T_LEN 4096
#define E_DIM 1024
#define HHID  512
#define PCOLS 4096
#define NEG_INF   -10000.0f
#define START_TAG 14
#define STOP_TAG  15

__device__ __forceinline__ float sigmoidf_(float x) { return 1.0f / (1.0f + expf(-x)); }

// ------------------------------------------------------------------
// K1: embedding gather + input projection GEMM (fp32, 64x64 tiles)
// P[t][r] = sum_k embed[sent[t]][k] * W[r][k] + (b_ih[r]+b_hh[r])
//   r in [0,2048): w_ih_f ; r in [2048,4096): w_ih_b
// ------------------------------------------------------------------
__global__ __launch_bounds__(256) void gemm_pre(
    const int* __restrict__ sent, const float* __restrict__ embed,
    const float* __restrict__ w_ih_f, const float* __restrict__ w_ih_b,
    const float* __restrict__ b_ih_f, const float* __restrict__ b_hh_f,
    const float* __restrict__ b_ih_b, const float* __restrict__ b_hh_b,
    float* __restrict__ P)
{
    __shared__ float As[16][68];
    __shared__ float Bs[16][68];
    const int tid = threadIdx.x;
    const int t0 = blockIdx.x * 64;
    const int n0 = blockIdx.y * 64;
    const int tx = tid & 15, ty = tid >> 4;
    const int lr = tid >> 2;            // 0..63 row within tile
    const int lk = (tid & 3) << 2;      // 0,4,8,12 k offset
    const float* asrc = embed + (size_t)sent[t0 + lr] * E_DIM;
    const int brow = n0 + lr;
    const float* bsrc = (brow < 2048) ? (w_ih_f + (size_t)brow * E_DIM)
                                      : (w_ih_b + (size_t)(brow - 2048) * E_DIM);
    float acc[4][4] = {};
    for (int k0 = 0; k0 < E_DIM; k0 += 16) {
        float4 av = *(const float4*)(asrc + k0 + lk);
        float4 bv = *(const float4*)(bsrc + k0 + lk);
        __syncthreads();
        As[lk+0][lr]=av.x; As[lk+1][lr]=av.y; As[lk+2][lr]=av.z; As[lk+3][lr]=av.w;
        Bs[lk+0][lr]=bv.x; Bs[lk+1][lr]=bv.y; Bs[lk+2][lr]=bv.z; Bs[lk+3][lr]=bv.w;
        __syncthreads();
        #pragma unroll
        for (int kk = 0; kk < 16; ++kk) {
            float4 a = *(const float4*)&As[kk][ty << 2];
            float4 b = *(const float4*)&Bs[kk][tx << 2];
            acc[0][0]+=a.x*b.x; acc[0][1]+=a.x*b.y; acc[0][2]+=a.x*b.z; acc[0][3]+=a.x*b.w;
            acc[1][0]+=a.y*b.x; acc[1][1]+=a.y*b.y; acc[1][2]+=a.y*b.z; acc[1][3]+=a.y*b.w;
            acc[2][0]+=a.z*b.x; acc[2][1]+=a.z*b.y; acc[2][2]+=a.z*b.z; acc[2][3]+=a.z*b.w;
            acc[3][0]+=a.w*b.x; acc[3][1]+=a.w*b.y; acc[3][2]+=a.w*b.z; acc[3][3]+=a.w*b.w;
        }
    }
    float bias[4];
    #pragma unroll
    for (int j = 0; j < 4; ++j) {
        int n = n0 + (tx << 2) + j;
        bias[j] = (n < 2048) ? (b_ih_f[n] + b_hh_f[n]) : (b_ih_b[n - 2048] + b_hh_b[n - 2048]);
    }
    #pragma unroll
    for (int i = 0; i < 4; ++i) {
        int t = t0 + (ty << 2) + i;
        float4 o = make_float4(acc[i][0] + bias[0], acc[i][1] + bias[1],
                               acc[i][2] + bias[2], acc[i][3] + bias[3]);
        *(float4*)&P[(size_t)t * PCOLS + n0 + (tx << 2)] = o;
    }
}

// ------------------------------------------------------------------
// K2: sequential bidirectional LSTM.
// 256 blocks: dir = bid&1, slice = bid>>1 (0..127). Block owns 4 hidden
// units -> 16 W_hh rows (i,f,g,o x 4 units) resident in LDS.
// h exchange: packed u64 {stamp=t+1, f32 bits} agent-scope atomics;
// ws poison 0xAAAAAAAA can never equal a valid stamp (1..4096).
// ------------------------------------------------------------------
__global__ __launch_bounds__(256) void lstm_seq(
    const float* __restrict__ P,
    const float* __restrict__ w_hh_f, const float* __restrict__ w_hh_b,
    const float* __restrict__ h0, const float* __restrict__ c0,
    u64* __restrict__ hspF, u64* __restrict__ hspB)
{
    __shared__ float wlds[16 * 514];   // 16 rows x 512, pad 2 (bank stagger)
    __shared__ float hstage[512];
    __shared__ float red[16][16];
    __shared__ float ps[2][16];
    const int tid = threadIdx.x;
    const int dir = blockIdx.x & 1;
    const int slice = blockIdx.x >> 1;   // 0..127
    const int u0 = slice << 2;           // 4 units per block
    const float* __restrict__ whh = dir ? w_hh_b : w_hh_f;
    u64* hsp = dir ? hspB : hspF;
    const int dirOff = dir << 11;

    {   // load weights: local row r = g*4+u  <->  global row g*512 + u0 + u
        const int r = tid & 15, seg = tid >> 4;         // 16 segs x 32 cols
        const int g = r >> 2, u = r & 3;
        const float* src = whh + (size_t)(g * HHID + u0 + u) * HHID + (seg << 5);
        float* dst = wlds + r * 514 + (seg << 5);
        #pragma unroll
        for (int k = 0; k < 32; k += 2) *(float2*)(dst + k) = *(const float2*)(src + k);
    }
    float c = 0.0f;
    if (tid < 4) c = c0[dir * HHID + u0 + tid];
    if (tid < 16) {
        const int g = tid >> 2, u = tid & 3;
        const int tt = dir ? (T_LEN - 1) : 0;
        ps[0][tid] = P[(size_t)tt * PCOLS + dirOff + g * HHID + u0 + u];
    }
    __syncthreads();

    for (int t = 0; t < T_LEN; ++t) {
        // ---- phase 1: stage h_t into LDS ----
        if (t == 0) {
            hstage[tid]       = h0[dir * HHID + tid];
            hstage[tid + 256] = h0[dir * HHID + tid + 256];
        } else {
            u64* p0 = hsp + (size_t)t * HHID + tid;
            u64* p1 = p0 + 256;
            u64 v0, v1;
            for (;;) {
                v0 = __hip_atomic_load(p0, __ATOMIC_RELAXED, __HIP_MEMORY_SCOPE_AGENT);
                if ((unsigned)(v0 >> 32) == (unsigned)t) break;
            }
            for (;;) {
                v1 = __hip_atomic_load(p1, __ATOMIC_RELAXED, __HIP_MEMORY_SCOPE_AGENT);
                if ((unsigned)(v1 >> 32) == (unsigned)t) break;
            }
            hstage[tid]       = __uint_as_float((unsigned)v0);
            hstage[tid + 256] = __uint_as_float((unsigned)v1);
        }
        __syncthreads();
        // ---- phase 2: prefetch next step's input-projection slice ----
        if (tid < 16 && t + 1 < T_LEN) {
            const int g = tid >> 2, u = tid & 3;
            const int tt = dir ? (T_LEN - 2 - t) : (t + 1);
            ps[(t + 1) & 1][tid] = P[(size_t)tt * PCOLS + dirOff + g * HHID + u0 + u];
        }
        // ---- phase 3: GEMV  (16 rows x 512, 16 segs of 32 cols) ----
        {
            const int r = tid & 15, seg = tid >> 4;
            const float* wr = wlds + r * 514 + (seg << 5);
            const float* hr = hstage + (seg << 5);
            float acc = 0.0f;
            #pragma unroll
            for (int k = 0; k < 32; k += 2) {
                float2 wv = *(const float2*)(wr + k);
                float2 hv = *(const float2*)(hr + k);
                acc += wv.x * hv.x;
                acc += wv.y * hv.y;
            }
            red[seg][r] = acc;
        }
        __syncthreads();
        // ---- phase 4: reduce + gates + publish (wave 0 only) ----
        if (tid < 64) {
            float rsum = 0.0f;
            if (tid < 16) {
                #pragma unroll
                for (int s = 0; s < 16; ++s) rsum += red[s][tid];
            }
            const int u = tid & 3;
            const float si = __shfl(rsum, u);
            const float sf = __shfl(rsum, 4 + u);
            const float sg = __shfl(rsum, 8 + u);
            const float so = __shfl(rsum, 12 + u);
            if (tid < 4) {
                const float* pp = ps[t & 1];
                const float ig = sigmoidf_(si + pp[u]);
                const float fg = sigmoidf_(sf + pp[4 + u]);
                const float gg = tanhf(sg + pp[8 + u]);
                const float og = sigmoidf_(so + pp[12 + u]);
                c = fg * c + ig * gg;
                const float h = og * tanhf(c);
                u64 pk = ((u64)(unsigned)(t + 1) << 32) | (u64)__float_as_uint(h);
                __hip_atomic_store(hsp + (size_t)(t + 1) * HHID + u0 + tid, pk,
                                   __ATOMIC_RELAXED, __HIP_MEMORY_SCOPE_AGENT);
            }
        }
    }
}

// ------------------------------------------------------------------
// K3: output projection  feats[t][k] = w_out[k] . [hf[t], hb[t]] + b_out[k]
// hf[t] = hspF[t+1], hb[t] = hspB[T-t]  (low 32 bits of packed words)
// ------------------------------------------------------------------
__global__ __launch_bounds__(256) void feats_kernel(
    const u64* __restrict__ hspF, const u64* __restrict__ hspB,
    const float* __restrict__ w_out, const float* __restrict__ b_out,
    float* __restrict__ feats)
{
    __shared__ float lst[1024];
    const int t = blockIdx.x;
    const int tid = threadIdx.x;
    {
        int e = tid;
        #pragma unroll
        for (int rnd = 0; rnd < 4; ++rnd, e += 256) {
            u64 v;
            if (e < 512)
                v = __hip_atomic_load((u64*)hspF + (size_t)(t + 1) * HHID + e,
                                      __ATOMIC_RELAXED, __HIP_MEMORY_SCOPE_AGENT);
            else
                v = __hip_atomic_load((u64*)hspB + (size_t)(T_LEN - t) * HHID + (e - 512),
                                      __ATOMIC_RELAXED, __HIP_MEMORY_SCOPE_AGENT);
            lst[e] = __uint_as_float((unsigned)v);
        }
    }
    __syncthreads();
    const int k = tid >> 4, s = tid & 15;
    const float* wr = w_out + (size_t)k * 1024 + (s << 6);
    const float* lr = lst + (s << 6);
    float acc = 0.0f;
    #pragma unroll
    for (int c4 = 0; c4 < 16; ++c4) {
        const int cc = ((c4 + s) & 15) << 2;   // stagger: avoid 16-way LDS bank conflict
        float4 w = *(const float4*)(wr + cc);
        float4 x = *(const float4*)(lr + cc);
        acc += w.x * x.x + w.y * x.y + w.z * x.z + w.w * x.w;
    }
    acc += __shfl_xor(acc, 1);
    acc += __shfl_xor(acc, 2);
    acc += __shfl_xor(acc, 4);
    acc += __shfl_xor(acc, 8);
    if (s == 0) feats[t * 16 + k] = acc + b_out[k];
}

// ------------------------------------------------------------------
// K4: Viterbi (K=16) + backtrace. One wave; lane = (tag i)*4 + jchunk.
// Exact numpy argmax tie semantics (first max = smallest index).
// ------------------------------------------------------------------
__global__ __launch_bounds__(64) void viterbi_kernel(
    const float* __restrict__ feats, const float* __restrict__ trans,
    float* __restrict__ out)
{
    __shared__ unsigned char bp[T_LEN][16];   // 64 KiB backpointers
    const int l = threadIdx.x;
    const int i = l >> 2, jc = l & 3;
    float tr[4], pj[4];
    #pragma unroll
    for (int m = 0; m < 4; ++m) {
        tr[m] = trans[i * 16 + jc + 4 * m];
        pj[m] = (jc + 4 * m == START_TAG) ? 0.0f : NEG_INF;
    }
    float fcur = feats[i];
    for (int t = 0; t < T_LEN; ++t) {
        float fnext = (t + 1 < T_LEN) ? feats[(t + 1) * 16 + i] : 0.0f;
        float bv = pj[0] + tr[0];
        int bj = jc;
        #pragma unroll
        for (int m = 1; m < 4; ++m) {
            float v = pj[m] + tr[m];
            if (v > bv) { bv = v; bj = jc + 4 * m; }
        }
        #pragma unroll
        for (int d = 1; d < 4; d <<= 1) {
            float ov = __shfl_xor(bv, d);
            int   oj = __shfl_xor(bj, d);
            if (ov > bv || (ov == bv && oj < bj)) { bv = ov; bj = oj; }
        }
        if (jc == 0) bp[t][i] = (unsigned char)bj;
        float newv = bv + fcur;
        fcur = fnext;
        #pragma unroll
        for (int m = 0; m < 4; ++m) pj[m] = __shfl(newv, (jc + 4 * m) << 2);
    }
    // terminal = prev + trans[STOP]; argmax (min-index ties)
    float bv = pj[0] + trans[STOP_TAG * 16 + jc];
    int bj = jc;
    #pragma unroll
    for (int m = 1; m < 4; ++m) {
        float v = pj[m] + trans[STOP_TAG * 16 + jc + 4 * m];
        if (v > bv) { bv = v; bj = jc + 4 * m; }
    }
    #pragma unroll
    for (int d = 1; d < 4; d <<= 1) {
        float ov = __shfl_xor(bv, d);
        int   oj = __shfl_xor(bj, d);
        if (ov > bv || (ov == bv && oj < bj)) { bv = ov; bj = oj; }
    }
    if (l == 0) {
        out[0] = bv;
        int tag = bj;
        out[1 + T_LEN - 1] = (float)tag;
        for (int t = T_LEN - 1; t >= 1; --t) {
            tag = bp[t][tag];
            out[1 + t - 1] = (float)tag;
        }
    }
}

// ------------------------------------------------------------------
extern "C" void kernel_launch(void* const* d_in, const int* in_sizes, int n_in,
                              void* d_out, int out_size, void* d_ws, size_t ws_size,
                              hipStream_t stream)
{
    const int*   sent   = (const int*)  d_in[0];
    const float* embed  = (const float*)d_in[1];
    const float* w_ih_f = (const float*)d_in[2];
    const float* w_hh_f = (const float*)d_in[3];
    const float* b_ih_f = (const float*)d_in[4];
    const float* b_hh_f = (const float*)d_in[5];
    const float* w_ih_b = (const float*)d_in[6];
    const float* w_hh_b = (const float*)d_in[7];
    const float* b_ih_b = (const float*)d_in[8];
    const float* b_hh_b = (const float*)d_in[9];
    const float* h0     = (const float*)d_in[10];
    const float* c0     = (const float*)d_in[11];
    const float* w_out  = (const float*)d_in[12];
    const float* b_out  = (const float*)d_in[13];
    const float* trans  = (const float*)d_in[14];

    char* ws = (char*)d_ws;
    float* P     = (float*)ws;                                        // 64 MiB
    u64*   hspF  = (u64*)(ws + (size_t)T_LEN * PCOLS * 4);            // 16.8 MiB
    u64*   hspB  = hspF + (size_t)(T_LEN + 1) * HHID;                 // 16.8 MiB
    float* feats = (float*)(hspB + (size_t)(T_LEN + 1) * HHID);       // 256 KiB
    float* outf  = (float*)d_out;

    gemm_pre<<<dim3(64, 64), 256, 0, stream>>>(sent, embed, w_ih_f, w_ih_b,
                                               b_ih_f, b_hh_f, b_ih_b, b_hh_b, P);
    lstm_seq<<<256, 256, 0, stream>>>(P, w_hh_f, w_hh_b, h0, c0, hspF, hspB);
    feats_kernel<<<T_LEN, 256, 0, stream>>>(hspF, hspB, w_out, b_out, feats);
    viterbi_kernel<<<1, 64, 0, stream>>>(feats, trans, outf);
}